// Round 7
// baseline (71.182 us; speedup 1.0000x reference)
//
#include <hip/hip_runtime.h>

#define C 128
#define CRED 32
#define K 7
#define KK 49
#define H 56
#define W 56
#define P (H*W)        // 3136
#define B 8
#define NPIX (B*P)     // 25088
#define BN_EPS 1e-5

// ---------------- fast-path ws layout (floats) ----------------
#define T_OFF 0
#define T_SIZE (B*CRED*P)                 // 802816
#define NBLK_A (49*B)                     // 392
#define PSUM_OFF (T_OFF + T_SIZE)
#define PSQ_OFF (PSUM_OFF + NBLK_A*CRED)
#define WS_NEED ((size_t)(PSQ_OFF + NBLK_A*CRED) * sizeof(float))

// fallback layout
#define FB_SCALE_OFF T_SIZE
#define FB_SHIFT_OFF (T_SIZE + CRED)

// ============ kA v3: t = w1*x + b1 + BN partials. No LDS; w1 via uniform scalar loads ============
// grid (49, B), block 256 = 64 px × 4 waves; wave rq owns 8 r.
__global__ __launch_bounds__(256) void kA_conv1(const float* __restrict__ x,
                                                const float* __restrict__ w1,
                                                const float* __restrict__ b1,
                                                float* __restrict__ ws) {
    int tid = threadIdx.x;
    int bx = blockIdx.x;
    int b  = blockIdx.y;
    int px = tid & 63;
    int p  = bx * 64 + px;                       // < P (49*64 == P)
    int ru8 = __builtin_amdgcn_readfirstlane((tid >> 6) * 8);   // wave-uniform r base
    const float* __restrict__ wq = w1 + (size_t)ru8 * C;        // uniform -> s_load
    const float* xb = x + (size_t)b * C * P + p;

    float acc[8];
#pragma unroll
    for (int u = 0; u < 8; ++u) acc[u] = 0.f;
#pragma unroll 8
    for (int c = 0; c < C; ++c) {
        float xv = xb[(size_t)c * P];
#pragma unroll
        for (int u = 0; u < 8; ++u)
            acc[u] = fmaf(wq[u * C + c], xv, acc[u]);
    }
#pragma unroll
    for (int u = 0; u < 8; ++u) acc[u] += b1[ru8 + u];

    float* tb = ws + T_OFF + (size_t)b * CRED * P + p;
#pragma unroll
    for (int u = 0; u < 8; ++u)
        tb[(size_t)(ru8 + u) * P] = acc[u];

    // exact fixed-tree wave reduction (wave == 64 px, 8 unique r per wave)
    float s[8], q[8];
#pragma unroll
    for (int u = 0; u < 8; ++u) { s[u] = acc[u]; q[u] = acc[u] * acc[u]; }
#pragma unroll
    for (int off = 32; off; off >>= 1) {
#pragma unroll
        for (int u = 0; u < 8; ++u) {
            s[u] += __shfl_xor(s[u], off);
            q[u] += __shfl_xor(q[u], off);
        }
    }
    if (px == 0) {
        int blk = b * 49 + bx;
        float* psum = ws + PSUM_OFF + (size_t)blk * CRED + ru8;
        float* psq  = ws + PSQ_OFF  + (size_t)blk * CRED + ru8;
#pragma unroll
        for (int u = 0; u < 8; ++u) { psum[u] = s[u]; psq[u] = q[u]; }
    }
}

// ============ kF: fused BN-finalize + register kern-gen + involution ============
// grid (64, 4): bx = b*8 + ht (7-row tile), by = z (32-ch chunk). block 448.
// Thread owns one pixel of the 7x56 tile; computes its own kern[49] in regs,
// then does the 49-tap involution for 8 float4 channel groups.
#define TH 7
#define XROWS 13          // TH + 6
#define XPITCH 68
__global__ __launch_bounds__(448) void kF_fused(const float* __restrict__ x,
                                                const float* __restrict__ w2,
                                                const float* __restrict__ b2,
                                                const float* __restrict__ gamma,
                                                const float* __restrict__ beta,
                                                const float* __restrict__ ws,
                                                float* __restrict__ out) {
    __shared__ float4 s_x[2][XROWS * XPITCH];   // 28288 B
    __shared__ double sd1[14][CRED];
    __shared__ double sd2[14][CRED];
    __shared__ float s_sc[CRED];
    __shared__ float s_sh[CRED];

    int tid = threadIdx.x;
    int bx = blockIdx.x;
    int z  = blockIdx.y;
    int b = bx >> 3, ht = bx & 7;
    int h0 = ht * TH;                     // 0..49
    int orow = tid / W;                   // 0..7 (7 = staging-only)
    int ocol = tid - orow * W;
    int sbase = orow * XPITCH + ocol;
    bool owns = orow < TH;                // tid < 392

    // staging geometry (branchless clamped offsets)
    int q0 = tid, q1 = tid + 448;
    int row0 = q0 >> 6, col0 = q0 & 63;
    int hh0 = h0 - 3 + row0, ww0 = col0 - 3;
    float m0 = ((unsigned)hh0 < H && (unsigned)ww0 < W) ? 1.f : 0.f;
    int off0 = (m0 != 0.f) ? (hh0 * W + ww0) : 0;
    int slot0 = row0 * XPITCH + col0;
    int row1 = q1 >> 6, col1 = q1 & 63;
    int hh1 = h0 - 3 + row1, ww1 = col1 - 3;
    bool in1 = q1 < XROWS * 64;           // 832
    float m1 = (in1 && (unsigned)hh1 < H && (unsigned)ww1 < W) ? 1.f : 0.f;
    int off1 = (m1 != 0.f) ? (hh1 * W + ww1) : 0;
    int slot1 = row1 * XPITCH + col1;

    int cg0 = z * 32;
    const size_t xbase = ((size_t)b * C + cg0) * P;

    // (1) issue prologue x loads FIRST (latency hidden under BN agg + kern-gen)
    const float* xc0 = x + xbase;
    float4 f0, f1;
    f0.x = xc0[off0] * m0;          f0.y = xc0[P + off0] * m0;
    f0.z = xc0[2 * P + off0] * m0;  f0.w = xc0[3 * P + off0] * m0;
    f1.x = xc0[off1] * m1;          f1.y = xc0[P + off1] * m1;
    f1.z = xc0[2 * P + off1] * m1;  f1.w = xc0[3 * P + off1] * m1;

    // (2) BN partial aggregation: 14 segs x 28 blocks, parallel over threads
    {
        int r = tid & 31, seg = tid >> 5;     // seg 0..13
        double s1 = 0.0, s2 = 0.0;
        for (int i = seg * 28; i < seg * 28 + 28; ++i) {
            s1 += (double)ws[PSUM_OFF + i * CRED + r];
            s2 += (double)ws[PSQ_OFF + i * CRED + r];
        }
        sd1[seg][r] = s1; sd2[seg][r] = s2;
    }
    __syncthreads();
    if (tid < CRED) {
        double S1 = 0.0, S2 = 0.0;
#pragma unroll
        for (int g = 0; g < 14; ++g) { S1 += sd1[g][tid]; S2 += sd2[g][tid]; }
        double mean = S1 / NPIX;
        double var = S2 / NPIX - mean * mean;
        double sc = (double)gamma[tid] / sqrt(var + BN_EPS);
        s_sc[tid] = (float)sc;
        s_sh[tid] = (float)((double)beta[tid] - mean * sc);
    }
    __syncthreads();

    // (3) per-thread kern-gen: load own pixel's t column, BN+relu, 49x32 matvec.
    // w2/b2 via wave-uniform scalar loads (K$), zero LDS.
    float kr[KK];
    {
        int pp = h0 * W + ((tid < 392) ? tid : 391);   // clamp staging-only threads
        const float* tp = ws + T_OFF + (size_t)b * CRED * P + pp;
        float tv[CRED];
#pragma unroll
        for (int r = 0; r < CRED; ++r) tv[r] = tp[(size_t)r * P];
#pragma unroll
        for (int r = 0; r < CRED; ++r)
            tv[r] = fmaxf(fmaf(tv[r], s_sc[r], s_sh[r]), 0.f);
#pragma unroll
        for (int k = 0; k < KK; ++k) {
            float a = b2[k];
#pragma unroll
            for (int r = 0; r < CRED; ++r)
                a = fmaf(w2[k * CRED + r], tv[r], a);
            kr[k] = a;
        }
    }

    // (4) commit prologue staging, then main channel loop
    s_x[0][slot0] = f0;
    if (in1) s_x[0][slot1] = f1;

    for (int it = 0; it < 8; ++it) {
        __syncthreads();
        float4 n0, n1;
        if (it < 7) {   // T14: issue next group's loads before compute
            const float* xc = x + xbase + (size_t)(it + 1) * 4 * P;
            n0.x = xc[off0] * m0;          n0.y = xc[P + off0] * m0;
            n0.z = xc[2 * P + off0] * m0;  n0.w = xc[3 * P + off0] * m0;
            n1.x = xc[off1] * m1;          n1.y = xc[P + off1] * m1;
            n1.z = xc[2 * P + off1] * m1;  n1.w = xc[3 * P + off1] * m1;
        }
        if (owns) {
            const float4* xs = s_x[it & 1] + sbase;
            float a0 = 0.f, a1 = 0.f, a2 = 0.f, a3 = 0.f;
#pragma unroll
            for (int i = 0; i < K; ++i) {
#pragma unroll
                for (int j = 0; j < K; ++j) {
                    float4 xv = xs[i * XPITCH + j];
                    float kv = kr[i * 7 + j];
                    a0 = fmaf(kv, xv.x, a0);
                    a1 = fmaf(kv, xv.y, a1);
                    a2 = fmaf(kv, xv.z, a2);
                    a3 = fmaf(kv, xv.w, a3);
                }
            }
            float* ob = out + xbase + (size_t)it * 4 * P + (size_t)h0 * W + tid;
            ob[0]     = a0;
            ob[P]     = a1;
            ob[2 * P] = a2;
            ob[3 * P] = a3;
        }
        if (it < 7) {
            float4* nb = s_x[(it + 1) & 1];
            nb[slot0] = n0;
            if (in1) nb[slot1] = n1;
        }
    }
}

// ===================== fallback (proven, needs only 3.3MB ws) =====================
__global__ __launch_bounds__(256) void k1_conv1(const float* __restrict__ x,
                                                const float* __restrict__ w1,
                                                const float* __restrict__ b1,
                                                float* __restrict__ t) {
    __shared__ float s_w1t[C * CRED];
    int tid = threadIdx.x;
    for (int i = tid; i < C * CRED; i += 256) {
        int c = i >> 5, r = i & 31;
        s_w1t[i] = w1[r * C + c];
    }
    __syncthreads();
    int b = blockIdx.y;
    int p = blockIdx.x * 256 + tid;
    if (p >= P) return;
    float acc[CRED];
#pragma unroll
    for (int r = 0; r < CRED; ++r) acc[r] = 0.f;
    const float* xb = x + (size_t)b * C * P + p;
    for (int c = 0; c < C; ++c) {
        float xv = xb[(size_t)c * P];
#pragma unroll
        for (int r = 0; r < CRED; ++r)
            acc[r] = fmaf(s_w1t[c * CRED + r], xv, acc[r]);
    }
    float* tb = t + (size_t)b * CRED * P + p;
#pragma unroll
    for (int r = 0; r < CRED; ++r)
        tb[(size_t)r * P] = acc[r] + b1[r];
}

__global__ __launch_bounds__(256) void k2_bnstats(const float* __restrict__ t,
                                                  const float* __restrict__ gamma,
                                                  const float* __restrict__ beta,
                                                  float* __restrict__ scale,
                                                  float* __restrict__ shift) {
    int r = blockIdx.x;
    int tid = threadIdx.x;
    double s = 0.0, s2 = 0.0;
    for (int i = tid; i < NPIX; i += 256) {
        int b = i / P, p = i - b * P;
        float v = t[((size_t)b * CRED + r) * P + p];
        s += v;
        s2 += (double)v * v;
    }
    __shared__ double ls[256], ls2[256];
    ls[tid] = s; ls2[tid] = s2;
    __syncthreads();
    for (int off = 128; off > 0; off >>= 1) {
        if (tid < off) { ls[tid] += ls[tid + off]; ls2[tid] += ls2[tid + off]; }
        __syncthreads();
    }
    if (tid == 0) {
        double mean = ls[0] / NPIX;
        double var = ls2[0] / NPIX - mean * mean;
        double sc = (double)gamma[r] / sqrt(var + BN_EPS);
        scale[r] = (float)sc;
        shift[r] = (float)((double)beta[r] - mean * sc);
    }
}

__global__ __launch_bounds__(256) void k3_involution(const float* __restrict__ x,
                                                     const float* __restrict__ t,
                                                     const float* __restrict__ scale,
                                                     const float* __restrict__ shift,
                                                     const float* __restrict__ w2,
                                                     const float* __restrict__ b2,
                                                     float* __restrict__ out) {
    int h = blockIdx.x;
    int b = blockIdx.y;
    int z = blockIdx.z;
    int tid = threadIdx.x;
    __shared__ float s_w2[KK * CRED];
    __shared__ float s_t[CRED * W];
    __shared__ float s_kern[KK][W];
    __shared__ float s_x[4][K][64];
    for (int i = tid; i < KK * CRED; i += 256) s_w2[i] = w2[i];
    for (int i = tid; i < CRED * W; i += 256) {
        int r = i / W, w = i - r * W;
        float v = t[((size_t)b * CRED + r) * P + h * W + w];
        v = fmaf(v, scale[r], shift[r]);
        s_t[r * W + w] = fmaxf(v, 0.f);
    }
    __syncthreads();
    for (int i = tid; i < KK * W; i += 256) {
        int k = i / W, w = i - k * W;
        float acc = b2[k];
#pragma unroll
        for (int r = 0; r < CRED; ++r)
            acc = fmaf(s_w2[k * CRED + r], s_t[r * W + w], acc);
        s_kern[k][w] = acc;
    }
    __syncthreads();
    int w = tid % W;
    int c4 = tid / W;
    float kr[KK];
#pragma unroll
    for (int k = 0; k < KK; ++k) kr[k] = s_kern[k][w];
    int cbase = z * (C / 2);
    for (int cg = cbase; cg < cbase + C / 2; cg += 4) {
        for (int i = tid; i < 4 * K * 64; i += 256) {
            int col = i & 63;
            int rc = i >> 6;
            int cc = rc / K;
            int row = rc - cc * K;
            int hh = h - 3 + row;
            int ww = col - 3;
            float v = 0.f;
            if ((unsigned)hh < H && (unsigned)ww < W)
                v = x[(((size_t)b * C + cg + cc) * H + hh) * W + ww];
            s_x[cc][row][col] = v;
        }
        __syncthreads();
        if (tid < 4 * W) {
            float acc = 0.f;
#pragma unroll
            for (int i = 0; i < K; ++i)
#pragma unroll
                for (int j = 0; j < K; ++j)
                    acc = fmaf(kr[i * K + j], s_x[c4][i][w + j], acc);
            out[(((size_t)b * C + cg + c4) * H + h) * W + w] = acc;
        }
        __syncthreads();
    }
}

extern "C" void kernel_launch(void* const* d_in, const int* in_sizes, int n_in,
                              void* d_out, int out_size, void* d_ws, size_t ws_size,
                              hipStream_t stream) {
    const float* x     = (const float*)d_in[0];
    const float* w1    = (const float*)d_in[1];
    const float* b1    = (const float*)d_in[2];
    const float* gamma = (const float*)d_in[3];
    const float* beta  = (const float*)d_in[4];
    const float* w2    = (const float*)d_in[5];
    const float* b2    = (const float*)d_in[6];
    float* out = (float*)d_out;
    float* ws  = (float*)d_ws;

    if (ws_size >= WS_NEED) {
        dim3 gA(49, B);
        kA_conv1<<<gA, 256, 0, stream>>>(x, w1, b1, ws);
        dim3 gF(64, 4);
        kF_fused<<<gF, 448, 0, stream>>>(x, w2, b2, gamma, beta, ws, out);
    } else {
        float* t     = ws;
        float* scale = ws + FB_SCALE_OFF;
        float* shift = ws + FB_SHIFT_OFF;
        dim3 g1((P + 255) / 256, B);
        k1_conv1<<<g1, 256, 0, stream>>>(x, w1, b1, t);
        k2_bnstats<<<CRED, 256, 0, stream>>>(t, gamma, beta, scale, shift);
        dim3 g3(H, B, 2);
        k3_involution<<<g3, 256, 0, stream>>>(x, t, scale, shift, w2, b2, out);
    }
}

// Round 8
// 47.667 us; speedup vs baseline: 1.4933x; 1.4933x over previous
//
#include <hip/hip_runtime.h>

#define C 128
#define CRED 32
#define K 7
#define KK 49
#define H 56
#define W 56
#define P (H*W)        // 3136
#define B 8
#define NPIX (B*P)     // 25088
#define BN_EPS 1e-5

// ---------------- fast-path ws layout (floats) ----------------
#define T_OFF 0
#define T_SIZE (B*CRED*P)                 // 802816
#define NBLK_A (49*B)                     // 392
#define PSUM_OFF (T_OFF + T_SIZE)
#define PSQ_OFF (PSUM_OFF + NBLK_A*CRED)
#define WS_NEED ((size_t)(PSQ_OFF + NBLK_A*CRED) * sizeof(float))

// fallback layout
#define FB_SCALE_OFF T_SIZE
#define FB_SHIFT_OFF (T_SIZE + CRED)

// ============ kA v3: t = w1*x + b1 + BN partials. No LDS; w1 via uniform scalar loads ============
// grid (49, B), block 256 = 64 px × 4 waves; wave rq owns 8 r.
__global__ __launch_bounds__(256) void kA_conv1(const float* __restrict__ x,
                                                const float* __restrict__ w1,
                                                const float* __restrict__ b1,
                                                float* __restrict__ ws) {
    int tid = threadIdx.x;
    int bx = blockIdx.x;
    int b  = blockIdx.y;
    int px = tid & 63;
    int p  = bx * 64 + px;                       // < P (49*64 == P)
    int ru8 = __builtin_amdgcn_readfirstlane((tid >> 6) * 8);   // wave-uniform r base
    const float* __restrict__ wq = w1 + (size_t)ru8 * C;        // uniform -> s_load
    const float* xb = x + (size_t)b * C * P + p;

    float acc[8];
#pragma unroll
    for (int u = 0; u < 8; ++u) acc[u] = 0.f;
#pragma unroll 8
    for (int c = 0; c < C; ++c) {
        float xv = xb[(size_t)c * P];
#pragma unroll
        for (int u = 0; u < 8; ++u)
            acc[u] = fmaf(wq[u * C + c], xv, acc[u]);
    }
#pragma unroll
    for (int u = 0; u < 8; ++u) acc[u] += b1[ru8 + u];

    float* tb = ws + T_OFF + (size_t)b * CRED * P + p;
#pragma unroll
    for (int u = 0; u < 8; ++u)
        tb[(size_t)(ru8 + u) * P] = acc[u];

    // exact fixed-tree wave reduction (wave == 64 px, 8 unique r per wave)
    float s[8], q[8];
#pragma unroll
    for (int u = 0; u < 8; ++u) { s[u] = acc[u]; q[u] = acc[u] * acc[u]; }
#pragma unroll
    for (int off = 32; off; off >>= 1) {
#pragma unroll
        for (int u = 0; u < 8; ++u) {
            s[u] += __shfl_xor(s[u], off);
            q[u] += __shfl_xor(q[u], off);
        }
    }
    if (px == 0) {
        int blk = b * 49 + bx;
        float* psum = ws + PSUM_OFF + (size_t)blk * CRED + ru8;
        float* psq  = ws + PSQ_OFF  + (size_t)blk * CRED + ru8;
#pragma unroll
        for (int u = 0; u < 8; ++u) { psum[u] = s[u]; psq[u] = q[u]; }
    }
}

// ============ kF v2: fused BN-finalize + register kern-gen + involution ============
// grid (64, 4): bx = b*8 + ht (7-row tile), by = z (32-ch chunk). block 448.
// __launch_bounds__(448, 1): grid is 256 blocks = 1 block/CU, so VGPRs are free
// up to ~256 — do NOT let the allocator cap at 64 and spill kr[49] (round-7 bug).
#define TH 7
#define XROWS 13          // TH + 6
#define XPITCH 68
__global__ __launch_bounds__(448, 1) void kF_fused(const float* __restrict__ x,
                                                   const float* __restrict__ w2,
                                                   const float* __restrict__ b2,
                                                   const float* __restrict__ gamma,
                                                   const float* __restrict__ beta,
                                                   const float* __restrict__ ws,
                                                   float* __restrict__ out) {
    __shared__ float4 s_x[2][XROWS * XPITCH];   // 28288 B
    __shared__ double sd1[14][CRED];
    __shared__ double sd2[14][CRED];
    __shared__ float s_sc[CRED];
    __shared__ float s_sh[CRED];

    int tid = threadIdx.x;
    int bx = blockIdx.x;
    int z  = blockIdx.y;
    int b = bx >> 3, ht = bx & 7;
    int h0 = ht * TH;                     // 0..49
    int orow = tid / W;                   // 0..7 (7 = staging-only)
    int ocol = tid - orow * W;
    int sbase = orow * XPITCH + ocol;
    bool owns = orow < TH;                // tid < 392

    // staging geometry (branchless clamped offsets)
    int q0 = tid, q1 = tid + 448;
    int row0 = q0 >> 6, col0 = q0 & 63;
    int hh0 = h0 - 3 + row0, ww0 = col0 - 3;
    float m0 = ((unsigned)hh0 < H && (unsigned)ww0 < W) ? 1.f : 0.f;
    int off0 = (m0 != 0.f) ? (hh0 * W + ww0) : 0;
    int slot0 = row0 * XPITCH + col0;
    int row1 = q1 >> 6, col1 = q1 & 63;
    int hh1 = h0 - 3 + row1, ww1 = col1 - 3;
    bool in1 = q1 < XROWS * 64;           // 832
    float m1 = (in1 && (unsigned)hh1 < H && (unsigned)ww1 < W) ? 1.f : 0.f;
    int off1 = (m1 != 0.f) ? (hh1 * W + ww1) : 0;
    int slot1 = row1 * XPITCH + col1;

    int cg0 = z * 32;
    const size_t xbase = ((size_t)b * C + cg0) * P;

    // (1) issue prologue x loads FIRST (latency hidden under BN agg + kern-gen)
    const float* xc0 = x + xbase;
    float4 f0, f1;
    f0.x = xc0[off0] * m0;          f0.y = xc0[P + off0] * m0;
    f0.z = xc0[2 * P + off0] * m0;  f0.w = xc0[3 * P + off0] * m0;
    f1.x = xc0[off1] * m1;          f1.y = xc0[P + off1] * m1;
    f1.z = xc0[2 * P + off1] * m1;  f1.w = xc0[3 * P + off1] * m1;

    // (2) BN partial aggregation: 14 segs x 28 blocks, parallel over threads
    {
        int r = tid & 31, seg = tid >> 5;     // seg 0..13
        double s1 = 0.0, s2 = 0.0;
        for (int i = seg * 28; i < seg * 28 + 28; ++i) {
            s1 += (double)ws[PSUM_OFF + i * CRED + r];
            s2 += (double)ws[PSQ_OFF + i * CRED + r];
        }
        sd1[seg][r] = s1; sd2[seg][r] = s2;
    }
    __syncthreads();
    if (tid < CRED) {
        double S1 = 0.0, S2 = 0.0;
#pragma unroll
        for (int g = 0; g < 14; ++g) { S1 += sd1[g][tid]; S2 += sd2[g][tid]; }
        double mean = S1 / NPIX;
        double var = S2 / NPIX - mean * mean;
        double sc = (double)gamma[tid] / sqrt(var + BN_EPS);
        s_sc[tid] = (float)sc;
        s_sh[tid] = (float)((double)beta[tid] - mean * sc);
    }
    __syncthreads();

    // (3) per-thread kern-gen, r-OUTER so only one tv scalar is live (no tv[32]):
    // kr[k] = b2[k] + sum_r w2[k][r] * relu(t[r]*sc[r]+sh[r]).
    // w2/b2 via wave-uniform scalar loads (K$), zero LDS, zero spill.
    float kr[KK];
#pragma unroll
    for (int k = 0; k < KK; ++k) kr[k] = b2[k];
    {
        int pp = h0 * W + ((tid < 392) ? tid : 391);   // clamp staging-only threads
        const float* tp = ws + T_OFF + (size_t)b * CRED * P + pp;
#pragma unroll 2
        for (int r = 0; r < CRED; ++r) {
            float tvr = tp[(size_t)r * P];
            tvr = fmaxf(fmaf(tvr, s_sc[r], s_sh[r]), 0.f);
#pragma unroll
            for (int k = 0; k < KK; ++k)
                kr[k] = fmaf(w2[k * CRED + r], tvr, kr[k]);
        }
    }

    // (4) commit prologue staging, then main channel loop
    s_x[0][slot0] = f0;
    if (in1) s_x[0][slot1] = f1;

    for (int it = 0; it < 8; ++it) {
        __syncthreads();
        float4 n0, n1;
        if (it < 7) {   // T14: issue next group's loads before compute
            const float* xc = x + xbase + (size_t)(it + 1) * 4 * P;
            n0.x = xc[off0] * m0;          n0.y = xc[P + off0] * m0;
            n0.z = xc[2 * P + off0] * m0;  n0.w = xc[3 * P + off0] * m0;
            n1.x = xc[off1] * m1;          n1.y = xc[P + off1] * m1;
            n1.z = xc[2 * P + off1] * m1;  n1.w = xc[3 * P + off1] * m1;
        }
        if (owns) {
            const float4* xs = s_x[it & 1] + sbase;
            float a0 = 0.f, a1 = 0.f, a2 = 0.f, a3 = 0.f;
#pragma unroll
            for (int i = 0; i < K; ++i) {
#pragma unroll
                for (int j = 0; j < K; ++j) {
                    float4 xv = xs[i * XPITCH + j];
                    float kv = kr[i * 7 + j];
                    a0 = fmaf(kv, xv.x, a0);
                    a1 = fmaf(kv, xv.y, a1);
                    a2 = fmaf(kv, xv.z, a2);
                    a3 = fmaf(kv, xv.w, a3);
                }
            }
            float* ob = out + xbase + (size_t)it * 4 * P + (size_t)h0 * W + tid;
            ob[0]     = a0;
            ob[P]     = a1;
            ob[2 * P] = a2;
            ob[3 * P] = a3;
        }
        if (it < 7) {
            float4* nb = s_x[(it + 1) & 1];
            nb[slot0] = n0;
            if (in1) nb[slot1] = n1;
        }
    }
}

// ===================== fallback (proven, needs only 3.3MB ws) =====================
__global__ __launch_bounds__(256) void k1_conv1(const float* __restrict__ x,
                                                const float* __restrict__ w1,
                                                const float* __restrict__ b1,
                                                float* __restrict__ t) {
    __shared__ float s_w1t[C * CRED];
    int tid = threadIdx.x;
    for (int i = tid; i < C * CRED; i += 256) {
        int c = i >> 5, r = i & 31;
        s_w1t[i] = w1[r * C + c];
    }
    __syncthreads();
    int b = blockIdx.y;
    int p = blockIdx.x * 256 + tid;
    if (p >= P) return;
    float acc[CRED];
#pragma unroll
    for (int r = 0; r < CRED; ++r) acc[r] = 0.f;
    const float* xb = x + (size_t)b * C * P + p;
    for (int c = 0; c < C; ++c) {
        float xv = xb[(size_t)c * P];
#pragma unroll
        for (int r = 0; r < CRED; ++r)
            acc[r] = fmaf(s_w1t[c * CRED + r], xv, acc[r]);
    }
    float* tb = t + (size_t)b * CRED * P + p;
#pragma unroll
    for (int r = 0; r < CRED; ++r)
        tb[(size_t)r * P] = acc[r] + b1[r];
}

__global__ __launch_bounds__(256) void k2_bnstats(const float* __restrict__ t,
                                                  const float* __restrict__ gamma,
                                                  const float* __restrict__ beta,
                                                  float* __restrict__ scale,
                                                  float* __restrict__ shift) {
    int r = blockIdx.x;
    int tid = threadIdx.x;
    double s = 0.0, s2 = 0.0;
    for (int i = tid; i < NPIX; i += 256) {
        int b = i / P, p = i - b * P;
        float v = t[((size_t)b * CRED + r) * P + p];
        s += v;
        s2 += (double)v * v;
    }
    __shared__ double ls[256], ls2[256];
    ls[tid] = s; ls2[tid] = s2;
    __syncthreads();
    for (int off = 128; off > 0; off >>= 1) {
        if (tid < off) { ls[tid] += ls[tid + off]; ls2[tid] += ls2[tid + off]; }
        __syncthreads();
    }
    if (tid == 0) {
        double mean = ls[0] / NPIX;
        double var = ls2[0] / NPIX - mean * mean;
        double sc = (double)gamma[r] / sqrt(var + BN_EPS);
        scale[r] = (float)sc;
        shift[r] = (float)((double)beta[r] - mean * sc);
    }
}

__global__ __launch_bounds__(256) void k3_involution(const float* __restrict__ x,
                                                     const float* __restrict__ t,
                                                     const float* __restrict__ scale,
                                                     const float* __restrict__ shift,
                                                     const float* __restrict__ w2,
                                                     const float* __restrict__ b2,
                                                     float* __restrict__ out) {
    int h = blockIdx.x;
    int b = blockIdx.y;
    int z = blockIdx.z;
    int tid = threadIdx.x;
    __shared__ float s_w2[KK * CRED];
    __shared__ float s_t[CRED * W];
    __shared__ float s_kern[KK][W];
    __shared__ float s_x[4][K][64];
    for (int i = tid; i < KK * CRED; i += 256) s_w2[i] = w2[i];
    for (int i = tid; i < CRED * W; i += 256) {
        int r = i / W, w = i - r * W;
        float v = t[((size_t)b * CRED + r) * P + h * W + w];
        v = fmaf(v, scale[r], shift[r]);
        s_t[r * W + w] = fmaxf(v, 0.f);
    }
    __syncthreads();
    for (int i = tid; i < KK * W; i += 256) {
        int k = i / W, w = i - k * W;
        float acc = b2[k];
#pragma unroll
        for (int r = 0; r < CRED; ++r)
            acc = fmaf(s_w2[k * CRED + r], s_t[r * W + w], acc);
        s_kern[k][w] = acc;
    }
    __syncthreads();
    int w = tid % W;
    int c4 = tid / W;
    float kr[KK];
#pragma unroll
    for (int k = 0; k < KK; ++k) kr[k] = s_kern[k][w];
    int cbase = z * (C / 2);
    for (int cg = cbase; cg < cbase + C / 2; cg += 4) {
        for (int i = tid; i < 4 * K * 64; i += 256) {
            int col = i & 63;
            int rc = i >> 6;
            int cc = rc / K;
            int row = rc - cc * K;
            int hh = h - 3 + row;
            int ww = col - 3;
            float v = 0.f;
            if ((unsigned)hh < H && (unsigned)ww < W)
                v = x[(((size_t)b * C + cg + cc) * H + hh) * W + ww];
            s_x[cc][row][col] = v;
        }
        __syncthreads();
        if (tid < 4 * W) {
            float acc = 0.f;
#pragma unroll
            for (int i = 0; i < K; ++i)
#pragma unroll
                for (int j = 0; j < K; ++j)
                    acc = fmaf(kr[i * K + j], s_x[c4][i][w + j], acc);
            out[(((size_t)b * C + cg + c4) * H + h) * W + w] = acc;
        }
        __syncthreads();
    }
}

extern "C" void kernel_launch(void* const* d_in, const int* in_sizes, int n_in,
                              void* d_out, int out_size, void* d_ws, size_t ws_size,
                              hipStream_t stream) {
    const float* x     = (const float*)d_in[0];
    const float* w1    = (const float*)d_in[1];
    const float* b1    = (const float*)d_in[2];
    const float* gamma = (const float*)d_in[3];
    const float* beta  = (const float*)d_in[4];
    const float* w2    = (const float*)d_in[5];
    const float* b2    = (const float*)d_in[6];
    float* out = (float*)d_out;
    float* ws  = (float*)d_ws;

    if (ws_size >= WS_NEED) {
        dim3 gA(49, B);
        kA_conv1<<<gA, 256, 0, stream>>>(x, w1, b1, ws);
        dim3 gF(64, 4);
        kF_fused<<<gF, 448, 0, stream>>>(x, w2, b2, gamma, beta, ws, out);
    } else {
        float* t     = ws;
        float* scale = ws + FB_SCALE_OFF;
        float* shift = ws + FB_SHIFT_OFF;
        dim3 g1((P + 255) / 256, B);
        k1_conv1<<<g1, 256, 0, stream>>>(x, w1, b1, t);
        k2_bnstats<<<CRED, 256, 0, stream>>>(t, gamma, beta, scale, shift);
        dim3 g3(H, B, 2);
        k3_involution<<<g3, 256, 0, stream>>>(x, t, scale, shift, w2, b2, out);
    }
}